// Round 6
// baseline (74.722 us; speedup 1.0000x reference)
//
#include <hip/hip_runtime.h>

#define HID 256
#define LK  2048
#define LQ  64
#define BSZ 8
#define M   16
#define NKEY (BSZ * M)   // 128
#define SPLIT 8          // compile-time: 1024 key blocks x 256 KB each

// ---------------------------------------------------------------------------
// Kernel 1:
//  blocks [0, BSZ): per-batch query column-sum + projection to u[b]
//        u[b][h] = sum_o (W_q qs[b] + Lq b_q)[o] * w_k[o][h]
//    float4-wide, wave-split with LDS cross-wave reduction (same structure
//    as the key path; each wave's 64 float4 lanes span ALL 256 columns,
//    so row/o splitting across waves is safe — unlike R2's bug where waves
//    owned disjoint column ranges).
//    Also zeroes amax[b] (ws is not re-poisoned between replays).
//  blocks [BSZ, BSZ + NKEY*SPLIT): key chunk column sums -> partial[kb][256]
// ---------------------------------------------------------------------------
__global__ void colsum_kernel(const float* __restrict__ query,
                              const float* __restrict__ key,
                              const float* __restrict__ w_q,
                              const float* __restrict__ b_q,
                              const float* __restrict__ w_k,
                              float* __restrict__ partial,
                              float* __restrict__ u,
                              unsigned long long* __restrict__ amax) {
    const int bid  = blockIdx.x;
    const int t    = threadIdx.x;
    const int wave = t >> 6;
    const int lane = t & 63;

    if (bid < BSZ) {
        // ---- query path ----
        if (t == 0) amax[bid] = 0ull;
        __shared__ float lds[4][HID];   // cross-wave reduce scratch
        __shared__ float qs[HID];
        __shared__ float qsv[HID];
        const int b = bid;
        const float* qbase = query + (size_t)b * LQ * HID;

        // Phase 1: qs[h] = sum_r query[b][r][h]; wave w sums rows [16w,16w+16)
        float4 a = make_float4(0.f, 0.f, 0.f, 0.f);
#pragma unroll
        for (int r = 0; r < LQ / 4; ++r) {
            float4 v = ((const float4*)(qbase + (size_t)(wave * (LQ / 4) + r) * HID))[lane];
            a.x += v.x; a.y += v.y; a.z += v.z; a.w += v.w;
        }
        ((float4*)lds[wave])[lane] = a;
        __syncthreads();
        qs[t] = (lds[0][t] + lds[1][t]) + (lds[2][t] + lds[3][t]);
        __syncthreads();

        // Phase 2: qsv[o] = dot(w_q[o,:], qs) + Lq*b_q[o]   (o = t)
        const float4* wrow = (const float4*)(w_q + (size_t)t * HID);
        float acc = 0.f;
#pragma unroll
        for (int h4 = 0; h4 < HID / 4; ++h4) {
            float4 w = wrow[h4];
            acc += w.x * qs[h4 * 4 + 0] + w.y * qs[h4 * 4 + 1]
                 + w.z * qs[h4 * 4 + 2] + w.w * qs[h4 * 4 + 3];
        }
        qsv[t] = acc + (float)LQ * b_q[t];
        __syncthreads();

        // Phase 3: u[h] = sum_o qsv[o]*w_k[o][h]; wave w covers o [64w,64w+64)
        float4 ua = make_float4(0.f, 0.f, 0.f, 0.f);
#pragma unroll 8
        for (int i = 0; i < 64; ++i) {
            const int o = wave * 64 + i;
            float4 w = ((const float4*)(w_k + (size_t)o * HID))[lane];
            const float q = qsv[o];
            ua.x += q * w.x; ua.y += q * w.y; ua.z += q * w.z; ua.w += q * w.w;
        }
        ((float4*)lds[wave])[lane] = ua;
        __syncthreads();
        u[(size_t)b * HID + t] = (lds[0][t] + lds[1][t]) + (lds[2][t] + lds[3][t]);
    } else {
        // ---- key path: column sum of a 256 KB rows-chunk ----
        const int kb    = bid - BSZ;
        const int n     = kb / SPLIT;
        const int chunk = kb % SPLIT;
        const int rows  = LK / SPLIT;           // 256
        const float* base = key + (size_t)n * LK * HID + (size_t)chunk * rows * HID;

        // wave w owns contiguous rows [w*64, w*64+64); 4 acc chains,
        // 16 float4 loads in flight per thread.
        const int rpw = rows / 4;               // 64
        const int r0  = wave * rpw;
        float4 a0 = make_float4(0.f, 0.f, 0.f, 0.f);
        float4 a1 = make_float4(0.f, 0.f, 0.f, 0.f);
        float4 a2 = make_float4(0.f, 0.f, 0.f, 0.f);
        float4 a3 = make_float4(0.f, 0.f, 0.f, 0.f);
#pragma unroll 4
        for (int i = 0; i < rpw; i += 4) {
            float4 v0 = ((const float4*)(base + (size_t)(r0 + i + 0) * HID))[lane];
            float4 v1 = ((const float4*)(base + (size_t)(r0 + i + 1) * HID))[lane];
            float4 v2 = ((const float4*)(base + (size_t)(r0 + i + 2) * HID))[lane];
            float4 v3 = ((const float4*)(base + (size_t)(r0 + i + 3) * HID))[lane];
            a0.x += v0.x; a0.y += v0.y; a0.z += v0.z; a0.w += v0.w;
            a1.x += v1.x; a1.y += v1.y; a1.z += v1.z; a1.w += v1.w;
            a2.x += v2.x; a2.y += v2.y; a2.z += v2.z; a2.w += v2.w;
            a3.x += v3.x; a3.y += v3.y; a3.z += v3.z; a3.w += v3.w;
        }
        a0.x = (a0.x + a1.x) + (a2.x + a3.x);
        a0.y = (a0.y + a1.y) + (a2.y + a3.y);
        a0.z = (a0.z + a1.z) + (a2.z + a3.z);
        a0.w = (a0.w + a1.w) + (a2.w + a3.w);

        __shared__ float klds[4][HID];
        ((float4*)klds[wave])[lane] = a0;
        __syncthreads();
        partial[(size_t)kb * HID + t] =
            (klds[0][t] + klds[1][t]) + (klds[2][t] + klds[3][t]);
    }
}

// ---------------------------------------------------------------------------
// Kernel 2: att = u[n/M] . (sum_c partial[n*SPLIT + c]); packed atomicMax
// into amax[b]: high 32 = monotone(float), low 32 = (M-1-m) so ties pick the
// smallest m (jnp.argmax first-max). Max is commutative -> replay-determ.
// ---------------------------------------------------------------------------
__global__ void att_kernel(const float* __restrict__ partial,
                           const float* __restrict__ u,
                           unsigned long long* __restrict__ amax) {
    const int n    = blockIdx.x;
    const int b    = n / M;
    const int m    = n % M;
    const int t    = threadIdx.x;
    const int wave = t >> 6;
    const int lane = t & 63;

    const float* p = partial + (size_t)n * SPLIT * HID + t;
    float s = 0.f;
    float sv[SPLIT];
#pragma unroll
    for (int c = 0; c < SPLIT; ++c) sv[c] = p[(size_t)c * HID];  // 8 indep loads
#pragma unroll
    for (int c = 0; c < SPLIT; ++c) s += sv[c];

    float v = s * u[(size_t)b * HID + t];
    for (int off = 32; off; off >>= 1) v += __shfl_down(v, off);

    __shared__ float wp[4];
    if (lane == 0) wp[wave] = v;
    __syncthreads();
    if (t == 0) {
        float att = (wp[0] + wp[1]) + (wp[2] + wp[3]);
        unsigned int fb = __float_as_uint(att);
        unsigned int mono = (fb & 0x80000000u) ? ~fb : (fb | 0x80000000u);
        unsigned long long pack =
            ((unsigned long long)mono << 32) | (unsigned int)(M - 1 - m);
        atomicMax(&amax[b], pack);
    }
}

// ---------------------------------------------------------------------------
// Kernel 3: decode winner from amax[b] (one broadcast load), float4 copy.
// ---------------------------------------------------------------------------
__global__ void gather_kernel(const float* __restrict__ key,
                              const unsigned long long* __restrict__ amax,
                              float* __restrict__ out) {
    const int b = blockIdx.y;
    const unsigned long long v = amax[b];          // same-address broadcast
    const int m = M - 1 - (int)(v & 0xFFFFFFFFu);
    const int n = b * M + m;
    const size_t per_b = (size_t)LK * HID / 4;     // 131072 float4s
    const size_t off = (size_t)blockIdx.x * blockDim.x + threadIdx.x;
    ((float4*)out)[(size_t)b * per_b + off] =
        ((const float4*)key)[(size_t)n * per_b + off];
}

extern "C" void kernel_launch(void* const* d_in, const int* in_sizes, int n_in,
                              void* d_out, int out_size, void* d_ws, size_t ws_size,
                              hipStream_t stream) {
    const float* query = (const float*)d_in[0];
    const float* key   = (const float*)d_in[1];
    const float* w_q   = (const float*)d_in[2];
    const float* b_q   = (const float*)d_in[3];
    const float* w_k   = (const float*)d_in[4];
    float* out = (float*)d_out;

    // ws layout (needs ~1.1 MB; R4 proved ws_size >= 16 MB): amax first (8B align)
    unsigned long long* amax = (unsigned long long*)d_ws;
    float* partial = (float*)(amax + BSZ);
    float* u       = partial + (size_t)NKEY * SPLIT * HID;

    hipLaunchKernelGGL(colsum_kernel, dim3(BSZ + NKEY * SPLIT), dim3(256), 0,
                       stream, query, key, w_q, b_q, w_k, partial, u, amax);

    hipLaunchKernelGGL(att_kernel, dim3(NKEY), dim3(256), 0, stream,
                       partial, u, amax);

    hipLaunchKernelGGL(gather_kernel, dim3(512, BSZ), dim3(256), 0, stream,
                       key, amax, out);
}

// Round 8
// 69.109 us; speedup vs baseline: 1.0812x; 1.0812x over previous
//
#include <hip/hip_runtime.h>
#include <hip/hip_cooperative_groups.h>

namespace cg = cooperative_groups;

#define HID 256
#define LK  2048
#define LQ  64
#define BSZ 8
#define M   16
#define NKEY (BSZ * M)        // 128
#define SPLIT 32              // key chunks per n
#define CHUNKS (NKEY * SPLIT) // 4096 chunks of 64 rows (64 KB) each
#define ROWS (LK / SPLIT)     // 64
#define RPW (ROWS / 4)        // 16 rows per wave
#define MAXC 4                // max chunks per block (nb >= 1024 guaranteed)

// ===========================================================================
// Fused cooperative kernel, one dispatch:
//  Phase A: every block grid-strides over 4096 key chunks; each chunk's
//           column-sum ends as ONE scalar per thread (column t), kept in
//           REGISTERS (csum[i]) — no partial buffer at all.
//           Block 0 zeroes att[128]. The LAST 8 blocks also run the query
//           path -> u[b] (they get the short end of the chunk division, so
//           the extra ~3us balances instead of adding a tail).
//  grid.sync()   (u + att-zero now visible everywhere)
//  Phase B: per saved chunk: v = csum . u[b]; block-reduce; one
//           atomicAdd(&att[n], v). 4096 atomics over 128 slots.
//  grid.sync()   (att final)
//  Phase C: per-block argmax of att via LDS (strict > == jnp first-max),
//           then grid-stride float4 copy of each b's winning key block.
// ===========================================================================
__global__ __launch_bounds__(256)
void fused_kernel(const float* __restrict__ query,
                  const float* __restrict__ key,
                  const float* __restrict__ w_q,
                  const float* __restrict__ b_q,
                  const float* __restrict__ w_k,
                  float* __restrict__ u,
                  float* __restrict__ att,
                  float* __restrict__ out,
                  int nb) {
    cg::grid_group grid = cg::this_grid();
    const int bid  = blockIdx.x;
    const int t    = threadIdx.x;
    const int wave = t >> 6;
    const int lane = t & 63;

    __shared__ float lds[4][HID];
    __shared__ float wp[4];

    // ---------------- Phase A ----------------
    if (bid == 0 && t < NKEY) att[t] = 0.f;   // ws not re-poisoned: zero per call

    float csum[MAXC];
    int   ccid[MAXC];
    int   nc = 0;
    for (int c = bid; c < CHUNKS; c += nb) {
        const int n  = c >> 5;              // /SPLIT
        const int ch = c & (SPLIT - 1);
        const float* base = key + (size_t)n * LK * HID + (size_t)ch * ROWS * HID;
        const int r0 = wave * RPW;

        float4 a0 = make_float4(0.f, 0.f, 0.f, 0.f);
        float4 a1 = make_float4(0.f, 0.f, 0.f, 0.f);
        float4 a2 = make_float4(0.f, 0.f, 0.f, 0.f);
        float4 a3 = make_float4(0.f, 0.f, 0.f, 0.f);
#pragma unroll 4
        for (int i = 0; i < RPW; i += 4) {
            float4 v0 = ((const float4*)(base + (size_t)(r0 + i + 0) * HID))[lane];
            float4 v1 = ((const float4*)(base + (size_t)(r0 + i + 1) * HID))[lane];
            float4 v2 = ((const float4*)(base + (size_t)(r0 + i + 2) * HID))[lane];
            float4 v3 = ((const float4*)(base + (size_t)(r0 + i + 3) * HID))[lane];
            a0.x += v0.x; a0.y += v0.y; a0.z += v0.z; a0.w += v0.w;
            a1.x += v1.x; a1.y += v1.y; a1.z += v1.z; a1.w += v1.w;
            a2.x += v2.x; a2.y += v2.y; a2.z += v2.z; a2.w += v2.w;
            a3.x += v3.x; a3.y += v3.y; a3.z += v3.z; a3.w += v3.w;
        }
        a0.x = (a0.x + a1.x) + (a2.x + a3.x);
        a0.y = (a0.y + a1.y) + (a2.y + a3.y);
        a0.z = (a0.z + a1.z) + (a2.z + a3.z);
        a0.w = (a0.w + a1.w) + (a2.w + a3.w);

        ((float4*)lds[wave])[lane] = a0;
        __syncthreads();
        csum[nc] = (lds[0][t] + lds[1][t]) + (lds[2][t] + lds[3][t]);
        ccid[nc] = c;
        ++nc;
        __syncthreads();   // lds reused next chunk / by query path
    }

    if (bid >= nb - BSZ) {
        // ---- query path -> u[qb] (R5-proven wave-split + LDS reduce) ----
        const int qb = bid - (nb - BSZ);
        __shared__ float qs[HID];
        __shared__ float qsv[HID];
        const float* qbase = query + (size_t)qb * LQ * HID;

        float4 a = make_float4(0.f, 0.f, 0.f, 0.f);
#pragma unroll
        for (int r = 0; r < LQ / 4; ++r) {
            float4 v = ((const float4*)(qbase + (size_t)(wave * (LQ / 4) + r) * HID))[lane];
            a.x += v.x; a.y += v.y; a.z += v.z; a.w += v.w;
        }
        ((float4*)lds[wave])[lane] = a;
        __syncthreads();
        qs[t] = (lds[0][t] + lds[1][t]) + (lds[2][t] + lds[3][t]);
        __syncthreads();

        const float4* wrow = (const float4*)(w_q + (size_t)t * HID);
        float acc = 0.f;
#pragma unroll
        for (int h4 = 0; h4 < HID / 4; ++h4) {
            float4 w = wrow[h4];
            acc += w.x * qs[h4 * 4 + 0] + w.y * qs[h4 * 4 + 1]
                 + w.z * qs[h4 * 4 + 2] + w.w * qs[h4 * 4 + 3];
        }
        qsv[t] = acc + (float)LQ * b_q[t];
        __syncthreads();

        float4 ua = make_float4(0.f, 0.f, 0.f, 0.f);
#pragma unroll 8
        for (int i = 0; i < 64; ++i) {
            const int o = wave * 64 + i;
            float4 w = ((const float4*)(w_k + (size_t)o * HID))[lane];
            const float q = qsv[o];
            ua.x += q * w.x; ua.y += q * w.y; ua.z += q * w.z; ua.w += q * w.w;
        }
        ((float4*)lds[wave])[lane] = ua;
        __syncthreads();
        u[(size_t)qb * HID + t] = (lds[0][t] + lds[1][t]) + (lds[2][t] + lds[3][t]);
    }

    grid.sync();

    // ---------------- Phase B: register chunk-sums . u -> att atomics ------
    for (int i = 0; i < nc; ++i) {
        const int n = ccid[i] >> 5;     // /SPLIT
        const int b = n >> 4;           // /M
        float v = csum[i] * u[(size_t)b * HID + t];
        for (int off = 32; off; off >>= 1) v += __shfl_down(v, off);
        if (lane == 0) wp[wave] = v;
        __syncthreads();
        if (t == 0) atomicAdd(&att[n], (wp[0] + wp[1]) + (wp[2] + wp[3]));
        __syncthreads();   // wp reused next i
    }

    grid.sync();

    // ---------------- Phase C: per-block argmax + gather -------------------
    __shared__ float satt[NKEY];
    __shared__ int   sbest[BSZ];
    if (t < NKEY) satt[t] = att[t];
    __syncthreads();
    if (t < BSZ) {
        const float* a = satt + t * M;
        int best = 0;
        float bv = a[0];
        for (int m = 1; m < M; ++m)
            if (a[m] > bv) { bv = a[m]; best = m; }  // strict >: first-max
        sbest[t] = best;
    }
    __syncthreads();

    const size_t total = (size_t)BSZ * LK * HID / 4;   // 1,048,576 float4s
    for (size_t i = (size_t)bid * blockDim.x + t; i < total;
         i += (size_t)nb * blockDim.x) {
        const int b = (int)(i >> 17);                  // per_b = 2^17 float4s
        const size_t off = i & (size_t)131071;
        const size_t n = (size_t)(b * M + sbest[b]);
        ((float4*)out)[i] = ((const float4*)key)[(n << 17) | off];
    }
}

// ======================= fallback: proven R4 3-kernel path ==================
__global__ void colsum_kernel(const float* __restrict__ query,
                              const float* __restrict__ key,
                              const float* __restrict__ w_q,
                              const float* __restrict__ b_q,
                              const float* __restrict__ w_k,
                              float* __restrict__ partial,
                              float* __restrict__ u,
                              unsigned long long* __restrict__ amax) {
    const int bid  = blockIdx.x;
    const int t    = threadIdx.x;
    const int wave = t >> 6;
    const int lane = t & 63;

    if (bid < BSZ) {
        if (t == 0) amax[bid] = 0ull;
        __shared__ float qs[HID];
        __shared__ float qsv[HID];
        const float* qbase = query + (size_t)bid * LQ * HID;
        float s = 0.f;
        for (int r = 0; r < LQ; ++r) s += qbase[(size_t)r * HID + t];
        qs[t] = s;
        __syncthreads();
        const float4* wrow = (const float4*)(w_q + (size_t)t * HID);
        float acc = 0.f;
#pragma unroll 8
        for (int h4 = 0; h4 < HID / 4; ++h4) {
            float4 w = wrow[h4];
            acc += w.x * qs[h4 * 4 + 0] + w.y * qs[h4 * 4 + 1]
                 + w.z * qs[h4 * 4 + 2] + w.w * qs[h4 * 4 + 3];
        }
        qsv[t] = acc + (float)LQ * b_q[t];
        __syncthreads();
        float uh = 0.f;
#pragma unroll 4
        for (int o = 0; o < HID; ++o) uh += qsv[o] * w_k[(size_t)o * HID + t];
        u[(size_t)bid * HID + t] = uh;
    } else {
        const int kb = bid - BSZ;
        const int n  = kb >> 5;
        const int ch = kb & (SPLIT - 1);
        const float* base = key + (size_t)n * LK * HID + (size_t)ch * ROWS * HID;
        const int r0 = wave * RPW;
        float4 a0 = make_float4(0.f, 0.f, 0.f, 0.f);
        float4 a1 = make_float4(0.f, 0.f, 0.f, 0.f);
        float4 a2 = make_float4(0.f, 0.f, 0.f, 0.f);
        float4 a3 = make_float4(0.f, 0.f, 0.f, 0.f);
#pragma unroll 4
        for (int i = 0; i < RPW; i += 4) {
            float4 v0 = ((const float4*)(base + (size_t)(r0 + i + 0) * HID))[lane];
            float4 v1 = ((const float4*)(base + (size_t)(r0 + i + 1) * HID))[lane];
            float4 v2 = ((const float4*)(base + (size_t)(r0 + i + 2) * HID))[lane];
            float4 v3 = ((const float4*)(base + (size_t)(r0 + i + 3) * HID))[lane];
            a0.x += v0.x; a0.y += v0.y; a0.z += v0.z; a0.w += v0.w;
            a1.x += v1.x; a1.y += v1.y; a1.z += v1.z; a1.w += v1.w;
            a2.x += v2.x; a2.y += v2.y; a2.z += v2.z; a2.w += v2.w;
            a3.x += v3.x; a3.y += v3.y; a3.z += v3.z; a3.w += v3.w;
        }
        a0.x = (a0.x + a1.x) + (a2.x + a3.x);
        a0.y = (a0.y + a1.y) + (a2.y + a3.y);
        a0.z = (a0.z + a1.z) + (a2.z + a3.z);
        a0.w = (a0.w + a1.w) + (a2.w + a3.w);
        __shared__ float klds[4][HID];
        ((float4*)klds[wave])[lane] = a0;
        __syncthreads();
        partial[(size_t)kb * HID + t] =
            (klds[0][t] + klds[1][t]) + (klds[2][t] + klds[3][t]);
    }
}

__global__ void att_kernel(const float* __restrict__ partial,
                           const float* __restrict__ u,
                           unsigned long long* __restrict__ amax) {
    const int n    = blockIdx.x;
    const int b    = n >> 4;
    const int m    = n & (M - 1);
    const int t    = threadIdx.x;
    const int wave = t >> 6;
    const int lane = t & 63;

    const float* p = partial + (size_t)n * SPLIT * HID + t;
    float s0 = 0.f, s1 = 0.f, s2 = 0.f, s3 = 0.f;
#pragma unroll
    for (int c = 0; c < SPLIT; c += 4) {
        s0 += p[(size_t)(c + 0) * HID];
        s1 += p[(size_t)(c + 1) * HID];
        s2 += p[(size_t)(c + 2) * HID];
        s3 += p[(size_t)(c + 3) * HID];
    }
    float v = ((s0 + s1) + (s2 + s3)) * u[(size_t)b * HID + t];
    for (int off = 32; off; off >>= 1) v += __shfl_down(v, off);
    __shared__ float wp[4];
    if (lane == 0) wp[wave] = v;
    __syncthreads();
    if (t == 0) {
        float att = (wp[0] + wp[1]) + (wp[2] + wp[3]);
        unsigned int fb = __float_as_uint(att);
        unsigned int mono = (fb & 0x80000000u) ? ~fb : (fb | 0x80000000u);
        unsigned long long pack =
            ((unsigned long long)mono << 32) | (unsigned int)(M - 1 - m);
        atomicMax(&amax[b], pack);
    }
}

__global__ void gather_kernel(const float* __restrict__ key,
                              const unsigned long long* __restrict__ amax,
                              float* __restrict__ out) {
    const int b = blockIdx.y;
    const unsigned long long v = amax[b];
    const int m = M - 1 - (int)(v & 0xFFFFFFFFu);
    const int n = b * M + m;
    const size_t per_b = (size_t)LK * HID / 4;
    const size_t off = (size_t)blockIdx.x * blockDim.x + threadIdx.x;
    ((float4*)out)[(size_t)b * per_b + off] =
        ((const float4*)key)[(size_t)n * per_b + off];
}

extern "C" void kernel_launch(void* const* d_in, const int* in_sizes, int n_in,
                              void* d_out, int out_size, void* d_ws, size_t ws_size,
                              hipStream_t stream) {
    const float* query = (const float*)d_in[0];
    const float* key   = (const float*)d_in[1];
    const float* w_q   = (const float*)d_in[2];
    const float* b_q   = (const float*)d_in[3];
    const float* w_k   = (const float*)d_in[4];
    float* out = (float*)d_out;

    // ws layout (shared by both paths): amax | att | u | partial
    unsigned long long* amax = (unsigned long long*)d_ws;
    float* att     = (float*)(amax + BSZ);
    float* u       = att + NKEY;
    float* partial = u + (size_t)BSZ * HID;

    int coop = 0;
    hipDeviceGetAttribute(&coop, hipDeviceAttributeCooperativeLaunch, 0);

    bool launched = false;
    if (coop) {
        int maxActive = 0;
        hipError_t oe = hipOccupancyMaxActiveBlocksPerMultiprocessor(
            &maxActive, (const void*)fused_kernel, 256, 0);
        int ncu = 0;
        hipDeviceGetAttribute(&ncu, hipDeviceAttributeMultiprocessorCount, 0);
        if (oe == hipSuccess && maxActive >= 1 && ncu >= 1) {
            long long cap = (long long)ncu * maxActive;  // strict co-residency
            int nb = (int)(cap > 2056 ? 2056 : cap);
            if (nb >= 1024 + BSZ) {   // guarantees <= MAXC chunks per block
                void* args[] = {(void*)&query, (void*)&key, (void*)&w_q,
                                (void*)&b_q,   (void*)&w_k, (void*)&u,
                                (void*)&att,   (void*)&out, (void*)&nb};
                hipError_t le = hipLaunchCooperativeKernel(
                    (const void*)fused_kernel, dim3(nb), dim3(256), args, 0,
                    stream);
                launched = (le == hipSuccess);
            }
        }
    }

    if (!launched) {
        hipLaunchKernelGGL(colsum_kernel, dim3(BSZ + CHUNKS), dim3(256), 0,
                           stream, query, key, w_q, b_q, w_k, partial, u, amax);
        hipLaunchKernelGGL(att_kernel, dim3(NKEY), dim3(256), 0, stream,
                           partial, u, amax);
        hipLaunchKernelGGL(gather_kernel, dim3(512, BSZ), dim3(256), 0, stream,
                           key, amax, out);
    }
}